// Round 16
// baseline (41.189 us; speedup 1.0000x reference)
//
#include <hip/hip_runtime.h>
#include <hip/hip_fp16.h>
#include <stdint.h>

#define B_    32
#define T_    1000
#define F_    80
#define COUT_ 64
#define NAUX_ 128
#define TO_   500
#define FO_   40
#define PSTR_ 12   // per-(b,c) param stride in u32: 9 dup-half2 taps + 1 f32 bias + 2 pad
#define CL_   8    // channels per block-column (register window reuse)

#define NFT (B_ * 576 * 16)        // filter-dot threads
#define NBT (B_ * 64 * 16)         // bias-dot threads

typedef float v4f __attribute__((ext_vector_type(4)));
typedef _Float16 h2v __attribute__((ext_vector_type(2)));
typedef __fp16 fp16x2 __attribute__((ext_vector_type(2)));   // cvt_pkrtz return type

static __device__ __forceinline__ uint32_t pk2(float lo, float hi) {
    fp16x2 pk = __builtin_amdgcn_cvt_pkrtz(lo, hi);
    return *(uint32_t*)&pk;
}

// Kernel 1: hypernetwork, 16 threads per dot product (8-elem partials + shfl reduce).
__global__ __launch_bounds__(256) void hyper_kernel(
    const float* __restrict__ aux,
    const float* __restrict__ Wg,
    const float* __restrict__ bg,
    const float* __restrict__ Wb,
    const float* __restrict__ bb,
    const int*   __restrict__ x_len,
    uint32_t* __restrict__ fw,
    float* __restrict__ l2_out)
{
    int t = blockIdx.x * blockDim.x + threadIdx.x;

    if (t < NFT) {
        int d = t >> 4, part = t & 15;
        int b = d / 576, idx = d % 576;
        const float* a = aux + b * NAUX_ + part * 8;
        const float* w = Wg + (size_t)idx * NAUX_ + part * 8;
        float4 a0 = *(const float4*)(a);
        float4 a1 = *(const float4*)(a + 4);
        float4 w0 = *(const float4*)(w);
        float4 w1 = *(const float4*)(w + 4);
        float s = a0.x * w0.x;
        s = fmaf(a0.y, w0.y, s);
        s = fmaf(a0.z, w0.z, s);
        s = fmaf(a0.w, w0.w, s);
        s = fmaf(a1.x, w1.x, s);
        s = fmaf(a1.y, w1.y, s);
        s = fmaf(a1.z, w1.z, s);
        s = fmaf(a1.w, w1.w, s);
        s += __shfl_xor(s, 1);
        s += __shfl_xor(s, 2);
        s += __shfl_xor(s, 4);
        s += __shfl_xor(s, 8);
        if (part == 0) {
            int c = idx / 9, k = idx % 9;
            uint32_t hu = (uint32_t)__half_as_ushort(__float2half_rn(s + bg[idx]));
            fw[(b * COUT_ + c) * PSTR_ + k] = hu | (hu << 16);
        }
    } else if (t < NFT + NBT) {
        int u = t - NFT;
        int d = u >> 4, part = u & 15;
        int b = d >> 6, c = d & 63;
        const float* a = aux + b * NAUX_ + part * 8;
        const float* w = Wb + (size_t)c * NAUX_ + part * 8;
        float4 a0 = *(const float4*)(a);
        float4 a1 = *(const float4*)(a + 4);
        float4 w0 = *(const float4*)(w);
        float4 w1 = *(const float4*)(w + 4);
        float s = a0.x * w0.x;
        s = fmaf(a0.y, w0.y, s);
        s = fmaf(a0.z, w0.z, s);
        s = fmaf(a0.w, w0.w, s);
        s = fmaf(a1.x, w1.x, s);
        s = fmaf(a1.y, w1.y, s);
        s = fmaf(a1.z, w1.z, s);
        s = fmaf(a1.w, w1.w, s);
        s += __shfl_xor(s, 1);
        s += __shfl_xor(s, 2);
        s += __shfl_xor(s, 4);
        s += __shfl_xor(s, 8);
        if (part == 0) fw[d * PSTR_ + 9] = __float_as_uint(s + bb[c]);
    } else if (t < NFT + NBT + B_) {
        int b = t - NFT - NBT;
        l2_out[b] = (float)(x_len[b] >> 1);
    }
}

// Kernel 2: conv(3x3,pad1)+bias+relu+pool(2x2,s2)+mask, TWO pooled rows per thread.
// Window: 6 input rows (4tp-1..4tp+4) x 10 cols -> 5 vertical half2 pairs x 10,
// pair P2 shared between the two pooled rows. Temporal stores (R15 lesson).
__global__ __launch_bounds__(256) void conv_pool_kernel(
    const float*    __restrict__ x,      // [B][T][F]
    const int*      __restrict__ x_len,
    const uint32_t* __restrict__ fw,     // [B*COUT][PSTR_] dup-half2 taps + f32 bias
    float* __restrict__ out)             // [B][COUT][TO][FO]
{
    const int bg  = blockIdx.y;       // b*8 + g
    const int b   = bg >> 3;
    const int bc0 = bg * CL_;         // b*64 + g*8

    int t = blockIdx.x * blockDim.x + threadIdx.x;   // [0, 2560)
    if (t >= 250 * 10) return;                       // 2500 active
    int f4 = t % 10;
    int tp = t / 10;                  // pooled-row pair index [0,250)
    int to0 = 2 * tp;                 // rows to0, to0+1

    float* obase = out + ((size_t)bc0 * TO_ + to0) * FO_ + 4 * f4;

    int l2 = x_len[b] >> 1;
    bool act0 = (to0 < l2), act1 = (to0 + 1 < l2);
    v4f z = (v4f){0.f, 0.f, 0.f, 0.f};

    if (!act0) {   // both rows masked (act0 false => act1 false)
        #pragma unroll
        for (int i = 0; i < CL_; ++i) {
            float* ob = obase + (size_t)i * (TO_ * FO_);
            *(v4f*)(ob) = z;
            *(v4f*)(ob + FO_) = z;
        }
        return;
    }

    // all channels' params up front: wave-uniform address -> s_load
    const uint32_t* p = fw + (size_t)bc0 * PSTR_;
    uint32_t prm[CL_][10];
    #pragma unroll
    for (int i = 0; i < CL_; ++i)
        #pragma unroll
        for (int k = 0; k < 10; ++k)
            prm[i][k] = p[i * PSTR_ + k];

    // 6x10 window rows 4tp-1 .. 4tp+4 (zero-padded at r<0, r>=T)
    float w[6][10];
    const float* xb = x + (size_t)b * (T_ * F_);
    const int cb = 8 * f4;
    #pragma unroll
    for (int i = 0; i < 6; ++i) {
        int r = 4 * tp - 1 + i;
        if (r < 0 || r >= T_) {
            #pragma unroll
            for (int j = 0; j < 10; ++j) w[i][j] = 0.f;
        } else {
            const float* rp = xb + r * F_ + cb;      // 16B-aligned
            w[i][0] = (f4 > 0) ? rp[-1] : 0.f;
            float4 m0 = *(const float4*)(rp);
            float4 m1 = *(const float4*)(rp + 4);
            w[i][1] = m0.x; w[i][2] = m0.y; w[i][3] = m0.z; w[i][4] = m0.w;
            w[i][5] = m1.x; w[i][6] = m1.y; w[i][7] = m1.z; w[i][8] = m1.w;
            w[i][9] = (f4 < 9) ? rp[8] : 0.f;
        }
    }

    // 5 vertical pair-rows: wp[k][c] = (w[k][c], w[k+1][c])
    __half2 wp[5][10];
    #pragma unroll
    for (int k = 0; k < 5; ++k)
        #pragma unroll
        for (int c = 0; c < 10; ++c) {
            uint32_t u = pk2(w[k][c], w[k + 1][c]);
            wp[k][c] = *(__half2*)&u;
        }

    #pragma unroll
    for (int i = 0; i < CL_; ++i) {
        __half2 flt[9];
        #pragma unroll
        for (int k = 0; k < 9; ++k)
            flt[k] = *(const __half2*)&prm[i][k];
        const float bias = __uint_as_float(prm[i][9]);

        float o0[4], o1[4];
        #pragma unroll
        for (int q = 0; q < 4; ++q) {
            // pooled row to0: pairs 0,1,2 ; pooled row to0+1: pairs 2,3,4
            __half2 a00 = __halves2half2(__ushort_as_half((unsigned short)0),
                                         __ushort_as_half((unsigned short)0));
            __half2 a01 = a00, a10 = a00, a11 = a00;
            #pragma unroll
            for (int ii = 0; ii < 3; ++ii) {
                #pragma unroll
                for (int jj = 0; jj < 3; ++jj) {
                    const __half2 f = flt[ii * 3 + jj];
                    a00 = __hfma2(f, wp[ii][2 * q + jj],         a00);
                    a01 = __hfma2(f, wp[ii][2 * q + 1 + jj],     a01);
                    a10 = __hfma2(f, wp[ii + 2][2 * q + jj],     a10);
                    a11 = __hfma2(f, wp[ii + 2][2 * q + 1 + jj], a11);
                }
            }
            h2v m0 = __builtin_elementwise_max(*(h2v*)&a00, *(h2v*)&a01);
            h2v m1 = __builtin_elementwise_max(*(h2v*)&a10, *(h2v*)&a11);
            o0[q] = fmaxf(fmaxf((float)m0.x, (float)m0.y) + bias, 0.f);
            o1[q] = fmaxf(fmaxf((float)m1.x, (float)m1.y) + bias, 0.f);
        }
        float* ob = obase + (size_t)i * (TO_ * FO_);
        *(v4f*)(ob) = (v4f){o0[0], o0[1], o0[2], o0[3]};
        *(v4f*)(ob + FO_) = act1 ? (v4f){o1[0], o1[1], o1[2], o1[3]} : z;
    }
}

extern "C" void kernel_launch(void* const* d_in, const int* in_sizes, int n_in,
                              void* d_out, int out_size, void* d_ws, size_t ws_size,
                              hipStream_t stream) {
    const float* x     = (const float*)d_in[0];
    const int*   x_len = (const int*)d_in[1];
    const float* aux   = (const float*)d_in[2];
    const float* Wg    = (const float*)d_in[3];
    const float* bg    = (const float*)d_in[4];
    const float* Wb    = (const float*)d_in[5];
    const float* bb    = (const float*)d_in[6];

    float*    out = (float*)d_out;
    uint32_t* fw  = (uint32_t*)d_ws;                       // B*COUT*PSTR_ u32 = 98 KB
    float* l2_out = out + (size_t)B_ * COUT_ * TO_ * FO_;  // tail: 32 floats

    // Kernel 1: 294912 + 32768 + 32 threads -> 1281 blocks
    {
        int total = NFT + NBT + B_;
        int blocks = (total + 255) / 256;
        hipLaunchKernelGGL(hyper_kernel, dim3(blocks), dim3(256), 0, stream,
                           aux, Wg, bg, Wb, bb, x_len, fw, l2_out);
    }
    // Kernel 2: grid (10, 256): 2560 threads per (b,g), 2500 active, 2 rows/thread
    {
        hipLaunchKernelGGL(conv_pool_kernel, dim3(10, 256), dim3(256), 0, stream,
                           x, x_len, fw, out);
    }
}

// Round 17
// 37.990 us; speedup vs baseline: 1.0842x; 1.0842x over previous
//
#include <hip/hip_runtime.h>
#include <hip/hip_fp16.h>
#include <stdint.h>

#define B_    32
#define T_    1000
#define F_    80
#define COUT_ 64
#define NAUX_ 128
#define TO_   500
#define FO_   40
#define PSTR_ 12   // per-(b,c) param stride in u32: 9 dup-half2 taps + 1 f32 bias + 2 pad
#define CL_   8    // channels per block-column (register window reuse)

#define NFT (B_ * 576 * 16)        // filter-dot threads
#define NBT (B_ * 64 * 16)         // bias-dot threads

typedef float v4f __attribute__((ext_vector_type(4)));
typedef _Float16 h2v __attribute__((ext_vector_type(2)));
typedef __fp16 fp16x2 __attribute__((ext_vector_type(2)));   // cvt_pkrtz return type

static __device__ __forceinline__ uint32_t pk2(float lo, float hi) {
    fp16x2 pk = __builtin_amdgcn_cvt_pkrtz(lo, hi);
    return *(uint32_t*)&pk;
}

// Kernel 1: hypernetwork, 16 threads per dot product (8-elem partials + shfl reduce).
// Filter taps stored as DUPLICATED half2 (h,h) in u32; bias stored as f32 bits.
__global__ __launch_bounds__(256) void hyper_kernel(
    const float* __restrict__ aux,
    const float* __restrict__ Wg,
    const float* __restrict__ bg,
    const float* __restrict__ Wb,
    const float* __restrict__ bb,
    const int*   __restrict__ x_len,
    uint32_t* __restrict__ fw,
    float* __restrict__ l2_out)
{
    int t = blockIdx.x * blockDim.x + threadIdx.x;

    if (t < NFT) {
        int d = t >> 4, part = t & 15;      // 16-lane groups wave-aligned
        int b = d / 576, idx = d % 576;
        const float* a = aux + b * NAUX_ + part * 8;
        const float* w = Wg + (size_t)idx * NAUX_ + part * 8;
        float4 a0 = *(const float4*)(a);
        float4 a1 = *(const float4*)(a + 4);
        float4 w0 = *(const float4*)(w);
        float4 w1 = *(const float4*)(w + 4);
        float s = a0.x * w0.x;
        s = fmaf(a0.y, w0.y, s);
        s = fmaf(a0.z, w0.z, s);
        s = fmaf(a0.w, w0.w, s);
        s = fmaf(a1.x, w1.x, s);
        s = fmaf(a1.y, w1.y, s);
        s = fmaf(a1.z, w1.z, s);
        s = fmaf(a1.w, w1.w, s);
        s += __shfl_xor(s, 1);
        s += __shfl_xor(s, 2);
        s += __shfl_xor(s, 4);
        s += __shfl_xor(s, 8);
        if (part == 0) {
            int c = idx / 9, k = idx % 9;
            uint32_t hu = (uint32_t)__half_as_ushort(__float2half_rn(s + bg[idx]));
            fw[(b * COUT_ + c) * PSTR_ + k] = hu | (hu << 16);
        }
    } else if (t < NFT + NBT) {
        int u = t - NFT;
        int d = u >> 4, part = u & 15;
        int b = d >> 6, c = d & 63;
        const float* a = aux + b * NAUX_ + part * 8;
        const float* w = Wb + (size_t)c * NAUX_ + part * 8;
        float4 a0 = *(const float4*)(a);
        float4 a1 = *(const float4*)(a + 4);
        float4 w0 = *(const float4*)(w);
        float4 w1 = *(const float4*)(w + 4);
        float s = a0.x * w0.x;
        s = fmaf(a0.y, w0.y, s);
        s = fmaf(a0.z, w0.z, s);
        s = fmaf(a0.w, w0.w, s);
        s = fmaf(a1.x, w1.x, s);
        s = fmaf(a1.y, w1.y, s);
        s = fmaf(a1.z, w1.z, s);
        s = fmaf(a1.w, w1.w, s);
        s += __shfl_xor(s, 1);
        s += __shfl_xor(s, 2);
        s += __shfl_xor(s, 4);
        s += __shfl_xor(s, 8);
        if (part == 0) fw[d * PSTR_ + 9] = __float_as_uint(s + bb[c]);
    } else if (t < NFT + NBT + B_) {
        int b = t - NFT - NBT;
        l2_out[b] = (float)(x_len[b] >> 1);
    }
}

// Kernel 2: fused conv(3x3,pad1) + bias + relu + maxpool(2x2,s2) + time mask.
// Packed-f16 math; all 8 channels' params loaded up front (wave-uniform -> SGPR),
// channel loop fully unrolled. Temporal stores (NT was ~25% slower — R15).
__global__ __launch_bounds__(256) void conv_pool_kernel(
    const float*    __restrict__ x,      // [B][T][F]
    const int*      __restrict__ x_len,
    const uint32_t* __restrict__ fw,     // [B*COUT][PSTR_] dup-half2 taps + f32 bias
    float* __restrict__ out)             // [B][COUT][TO][FO]
{
    const int bg  = blockIdx.y;       // b*8 + g
    const int b   = bg >> 3;
    const int bc0 = bg * CL_;         // b*64 + g*8

    int t = blockIdx.x * blockDim.x + threadIdx.x;   // [0, 5120)
    if (t >= TO_ * 10) return;                       // 5000 active
    int f4 = t % 10;
    int to = t / 10;

    float* obase = out + ((size_t)bc0 * TO_ + to) * FO_ + 4 * f4;

    int l2 = x_len[b] >> 1;
    if (to >= l2) {
        v4f z = (v4f){0.f, 0.f, 0.f, 0.f};
        #pragma unroll
        for (int i = 0; i < CL_; ++i)
            *(v4f*)(obase + (size_t)i * (TO_ * FO_)) = z;
        return;
    }

    // all channels' params up front: wave-uniform address -> s_load into SGPRs
    const uint32_t* p = fw + (size_t)bc0 * PSTR_;
    uint32_t prm[CL_][10];
    #pragma unroll
    for (int i = 0; i < CL_; ++i)
        #pragma unroll
        for (int k = 0; k < 10; ++k)
            prm[i][k] = p[i * PSTR_ + k];

    // 4x10 input window: rows 2to-1..2to+2, input cols 8f4-1..8f4+8 (zero-padded)
    float w[4][10];
    const float* xb = x + (size_t)b * (T_ * F_);
    const int cb = 8 * f4;
    #pragma unroll
    for (int i = 0; i < 4; ++i) {
        int r = 2 * to - 1 + i;
        if (r < 0 || r >= T_) {
            #pragma unroll
            for (int j = 0; j < 10; ++j) w[i][j] = 0.f;
        } else {
            const float* rp = xb + r * F_ + cb;      // 16B-aligned
            w[i][0] = (f4 > 0) ? rp[-1] : 0.f;
            float4 m0 = *(const float4*)(rp);
            float4 m1 = *(const float4*)(rp + 4);
            w[i][1] = m0.x; w[i][2] = m0.y; w[i][3] = m0.z; w[i][4] = m0.w;
            w[i][5] = m1.x; w[i][6] = m1.y; w[i][7] = m1.z; w[i][8] = m1.w;
            w[i][9] = (f4 < 9) ? rp[8] : 0.f;
        }
    }

    // vertical half2 pairs via single-inst packed cvt: wp[ii][c] = (w[ii][c], w[ii+1][c])
    __half2 wp[3][10];
    #pragma unroll
    for (int ii = 0; ii < 3; ++ii)
        #pragma unroll
        for (int c = 0; c < 10; ++c) {
            uint32_t u = pk2(w[ii][c], w[ii + 1][c]);
            wp[ii][c] = *(__half2*)&u;
        }

    #pragma unroll
    for (int i = 0; i < CL_; ++i) {
        __half2 flt[9];
        #pragma unroll
        for (int k = 0; k < 9; ++k)
            flt[k] = *(const __half2*)&prm[i][k];    // duplicated (h,h), from SGPR
        const float bias = __uint_as_float(prm[i][9]);

        float o[4];
        #pragma unroll
        for (int q = 0; q < 4; ++q) {
            __half2 acc0 = __halves2half2(__ushort_as_half((unsigned short)0),
                                          __ushort_as_half((unsigned short)0));
            __half2 acc1 = acc0;
            #pragma unroll
            for (int ii = 0; ii < 3; ++ii) {
                #pragma unroll
                for (int jj = 0; jj < 3; ++jj) {
                    const __half2 f = flt[ii * 3 + jj];
                    acc0 = __hfma2(f, wp[ii][2 * q + jj],     acc0);  // (s00,s10)
                    acc1 = __hfma2(f, wp[ii][2 * q + 1 + jj], acc1);  // (s01,s11)
                }
            }
            h2v m2 = __builtin_elementwise_max(*(h2v*)&acc0, *(h2v*)&acc1);
            float m = fmaxf((float)m2.x, (float)m2.y);
            o[q] = fmaxf(m + bias, 0.f);
        }
        v4f ov = (v4f){o[0], o[1], o[2], o[3]};
        *(v4f*)(obase + (size_t)i * (TO_ * FO_)) = ov;
    }
}

extern "C" void kernel_launch(void* const* d_in, const int* in_sizes, int n_in,
                              void* d_out, int out_size, void* d_ws, size_t ws_size,
                              hipStream_t stream) {
    const float* x     = (const float*)d_in[0];
    const int*   x_len = (const int*)d_in[1];
    const float* aux   = (const float*)d_in[2];
    const float* Wg    = (const float*)d_in[3];
    const float* bg    = (const float*)d_in[4];
    const float* Wb    = (const float*)d_in[5];
    const float* bb    = (const float*)d_in[6];

    float*    out = (float*)d_out;
    uint32_t* fw  = (uint32_t*)d_ws;                       // B*COUT*PSTR_ u32 = 98 KB
    float* l2_out = out + (size_t)B_ * COUT_ * TO_ * FO_;  // tail: 32 floats

    // Kernel 1: 294912 + 32768 + 32 threads -> 1281 blocks
    {
        int total = NFT + NBT + B_;
        int blocks = (total + 255) / 256;
        hipLaunchKernelGGL(hyper_kernel, dim3(blocks), dim3(256), 0, stream,
                           aux, Wg, bg, Wb, bb, x_len, fw, l2_out);
    }
    // Kernel 2: grid (20, 256) = 5120 threads per (b,g), 256 (b,g) pairs
    {
        hipLaunchKernelGGL(conv_pool_kernel, dim3(20, 256), dim3(256), 0, stream,
                           x, x_len, fw, out);
    }
}